// Round 17
// baseline (267.053 us; speedup 1.0000x reference)
//
#include <hip/hip_runtime.h>
#include <math.h>

namespace {

constexpr int D  = 768;
constexpr int H  = 12;
constexpr int B  = 8;
constexpr int LM = 512;
constexpr int LP = 1024;
constexpr int KV_LD = 1536;  // fused K|V projection row stride

typedef __attribute__((ext_vector_type(8))) short bf16x8;
typedef __attribute__((ext_vector_type(4))) float f32x4;
typedef unsigned short u16;

__device__ inline u16 f2bf(float f) {
  union { float f; unsigned u; } v;
  v.f = f;
  unsigned r = v.u + 0x7FFFu + ((v.u >> 16) & 1u);
  return (u16)(r >> 16);
}

__device__ inline unsigned long long pack4bf(float a, float b, float c, float d) {
  union { u16 h[4]; unsigned long long ll; } u;
  u.h[0] = f2bf(a); u.h[1] = f2bf(b); u.h[2] = f2bf(c); u.h[3] = f2bf(d);
  return u.ll;
}

__device__ inline float bf2f(u16 h) {
  union { unsigned u; float f; } v;
  v.u = ((unsigned)h) << 16;
  return v.f;
}

__device__ inline void gload16(const void* g, void* l) {
  __builtin_amdgcn_global_load_lds((const __attribute__((address_space(1))) void*)g,
                                   (__attribute__((address_space(3))) void*)l,
                                   16, 0, 0);
}

__device__ inline float wave_reduce_sum(float v) {
#pragma unroll
  for (int o = 1; o < 64; o <<= 1) v += __shfl_xor(v, o, 64);
  return v;
}

// ---------------------------------------------------------------------------
// Shared GEMM body: (32*WM) x 128 tile, BK=64, 256 threads (4 waves, 2x2).
// Double-buffered LDS, 2-phase pipeline.  Swapped-operand MFMA: lane holds
// C[row = wr+m*16+l15][col = wc+n*16+g*4+j] -> vectorized epilogue stores.
// T2 XOR swizzle via pre-swizzled global source (r11 fix, 7.1M->~0 LDS bank
// conflicts): write col-block (L&7)^(L>>3), read col-block (kk*4+g)^(l15&7).
// K-range [kbeg,kend) enables split-K callers.  bias may be runtime-null.
// sm must hold 2 * (32*WM + 128) * 64 u16 elements.  WM in {1,2,4}.
// ---------------------------------------------------------------------------
template <int EPI, bool OF32, bool OB16, int WM>
__device__ __forceinline__ void gemm_body(
    u16* sm, const u16* __restrict__ A, const u16* __restrict__ Bt,
    const float* __restrict__ bias, float* __restrict__ Cf,
    u16* __restrict__ Cb, int kbeg, int kend,
    int ldA, int ldB, int ldC, int bm, int bn) {
  constexpr int TMh = 32 * WM;
  constexpr int SSZ = (TMh + 128) * 64;
  const int tid = threadIdx.x, wv = tid >> 6, lane = tid & 63;
  const int l15 = lane & 15, g = lane >> 4;
  const int wr = (wv >> 1) * (16 * WM), wc = (wv & 1) * 64;

  f32x4 acc[WM][4];
  const f32x4 z4 = {0.f, 0.f, 0.f, 0.f};
#pragma unroll
  for (int m = 0; m < WM; ++m)
#pragma unroll
    for (int n = 0; n < 4; ++n) acc[m][n] = z4;

  // pre-swizzled global source column block: (lane&7) ^ (lane>>3)
  const int swz = (((lane & 7) ^ (lane >> 3))) * 8;
  const u16* Ab = A + (size_t)(bm + wv * 8 * WM + (lane >> 3)) * ldA + swz;
  const u16* Bb = Bt + (size_t)(bn + wv * 32 + (lane >> 3)) * ldB + swz;

  auto stage = [&](int buf, int k0) {
    u16* as = sm + buf * SSZ;
    u16* bs = as + TMh * 64;
#pragma unroll
    for (int i = 0; i < WM; ++i)
      gload16(Ab + (size_t)i * 8 * ldA + k0, &as[(wv * 8 * WM + i * 8) * 64]);
#pragma unroll
    for (int i = 0; i < 4; ++i)
      gload16(Bb + (size_t)i * 8 * ldB + k0, &bs[(wv * 32 + i * 8) * 64]);
  };

  stage(0, kbeg);
  int cur = 0;
  for (int k0 = kbeg; k0 < kend; k0 += 64) {
    __syncthreads();
    if (k0 + 64 < kend) stage(cur ^ 1, k0 + 64);
    const u16* as = sm + cur * SSZ;
    const u16* bs = as + TMh * 64;
#pragma unroll
    for (int kk = 0; kk < 2; ++kk) {
      // swizzled read col-block: (kk*4+g) ^ (row&7), row&7 == l15&7
      const int krd = ((kk * 4 + g) ^ (l15 & 7)) * 8;
      bf16x8 af[WM], bfr[4];
#pragma unroll
      for (int m = 0; m < WM; ++m)
        af[m] = *(const bf16x8*)&as[(wr + m * 16 + l15) * 64 + krd];
#pragma unroll
      for (int n = 0; n < 4; ++n)
        bfr[n] = *(const bf16x8*)&bs[(wc + n * 16 + l15) * 64 + krd];
#pragma unroll
      for (int m = 0; m < WM; ++m)
#pragma unroll
        for (int n = 0; n < 4; ++n)
          acc[m][n] =
              __builtin_amdgcn_mfma_f32_16x16x32_bf16(bfr[n], af[m], acc[m][n], 0, 0, 0);
    }
    cur ^= 1;
  }

#pragma unroll
  for (int m = 0; m < WM; ++m) {
    const size_t rr = bm + wr + m * 16 + l15;
#pragma unroll
    for (int n = 0; n < 4; ++n) {
      const int cc = bn + wc + n * 16 + g * 4;
      float v[4];
#pragma unroll
      for (int j = 0; j < 4; ++j) {
        float x = acc[m][n][j];
        if (EPI >= 1 && bias != nullptr) x += bias[cc + j];
        if (EPI == 2) x = 0.5f * x * (1.f + erff(x * 0.70710678118654752f));
        v[j] = x;
      }
      if (OF32) *(float4*)(Cf + rr * ldC + cc) = *(const float4*)v;
      if (OB16)
        *(unsigned long long*)(Cb + rr * ldC + cc) = pack4bf(v[0], v[1], v[2], v[3]);
    }
  }
}

// Generic GEMM kernel (XCD-swizzled when grid %8==0).
template <int EPI, bool OF32, bool OB16, int WM>
__global__ __launch_bounds__(256) void gemm_bf16(
    const u16* __restrict__ A, const u16* __restrict__ Bt,
    const float* __restrict__ bias, float* __restrict__ Cf,
    u16* __restrict__ Cb, int K, int ldA, int ldB, int ldC) {
  __shared__ u16 smem[2 * (32 * WM + 128) * 64];
  int bx, by;
  {
    const int total = gridDim.x * gridDim.y;
    const int flat = blockIdx.y * gridDim.x + blockIdx.x;
    if ((total & 7) == 0) {
      const int s = (flat & 7) * (total >> 3) + (flat >> 3);
      bx = s % gridDim.x;
      by = s / gridDim.x;
    } else {
      bx = blockIdx.x;
      by = blockIdx.y;
    }
  }
  gemm_body<EPI, OF32, OB16, WM>(smem, A, Bt, bias, Cf, Cb,
                                 0, K, ldA, ldB, ldC, by * 32 * WM, bx * 128);
}

// Merged Q + KV projection: one dispatch, WM=2 (64x128 tiles), 1920 blocks
// (384 Q + 1536 KV), 48KB LDS -> 3 blocks/CU (r16b: was WM=4 at 2/CU).
__global__ __launch_bounds__(256) void gemm_qkv(
    const u16* __restrict__ molb, const u16* __restrict__ protb,
    const u16* __restrict__ Wqt, const u16* __restrict__ Wkvt,
    u16* __restrict__ Qb16, u16* __restrict__ KVb16) {
  __shared__ u16 smem[2 * (64 + 128) * 64];
  const int flat = blockIdx.x;                     // 0..1919
  const int s = (flat & 7) * 240 + (flat >> 3);    // XCD chunking (1920/8)
  if (s < 384) {
    gemm_body<0, false, true, 2>(smem, molb, Wqt, nullptr,
                                 nullptr, Qb16, 0, D, D, D, D,
                                 (s / 6) * 64, (s % 6) * 128);
  } else {
    const int t2 = s - 384;                        // 0..1535
    gemm_body<0, false, true, 2>(smem, protb, Wkvt, nullptr,
                                 nullptr, KVb16, 0, D, D, D, KV_LD,
                                 (t2 / 12) * 64, (t2 % 12) * 128);
  }
}

// FFN2 split-K (K=3072 -> 2x1536): z=0 writes C0 (with bias), z=1 writes C1.
// WM=1 (32x128 tile), grid 6x128x2 = 1536 blocks, 40KB LDS -> 4/CU.
// Deterministic (no atomics); LN2 sums the partials.
__global__ __launch_bounds__(256) void gemm_ffn2(
    const u16* __restrict__ A, const u16* __restrict__ Bt,
    const float* __restrict__ bias, float* __restrict__ C0,
    float* __restrict__ C1) {
  __shared__ u16 smem[2 * (32 + 128) * 64];
  const int gx = 6, gy = 128;
  const int total = gx * gy * 2;
  const int flat = (blockIdx.z * gy + blockIdx.y) * gx + blockIdx.x;
  const int s = (flat & 7) * (total >> 3) + (flat >> 3);
  const int bx = s % gx;
  const int rem = s / gx;
  const int by = rem % gy;
  const int bz = rem / gy;
  float* Cf = bz ? C1 : C0;
  const float* bb = bz ? nullptr : bias;
  gemm_body<1, true, false, 1>(smem, A, Bt, bb, Cf, nullptr,
                               bz * 1536, bz * 1536 + 1536, 4 * D, 4 * D, D,
                               by * 32, bx * 128);
}

// ---------------------------------------------------------------------------
// Fused attention (r14 base + r16b store/PV interleave):
// per block = (16 q-rows, one (b,h)).  4 waves, each owns a 256-key slice.
// Swapped QK^T (mfma(K,Q)); in-lane softmax + 2 shfl; pack bf16 P to LDS;
// PV loop with 2 NT writeout rows interleaved per s-iteration.
// vmcnt is FIFO: a 16-store blob before PV makes each V-load wait drain up
// to 16 HBM stores (r14); end-of-kernel placement exposes the drain at the
// final barrier (r15, +12us).  Interleaving bounds each wait's drain to <=2
// stores and overlaps the rest under the previous iteration's MFMA.
// 1D grid 3072 with bijective XCD swizzle (each XCD owns 12 whole heads).
// ---------------------------------------------------------------------------
union WaveMem {
  u16 P[16][264];     // 8448 B (row stride 528 B -> 16B-aligned rows)
  float ao[16][68];   // 4352 B
};

__global__ __launch_bounds__(256, 4) void fattn(const u16* __restrict__ Qb,
                                                const u16* __restrict__ KVb,
                                                const u16* __restrict__ Vt,
                                                const float* __restrict__ sadd_g,
                                                float* __restrict__ attnw,
                                                u16* __restrict__ AOb) {
  __shared__ float smask[LP];                     // 4 KB additive mask (LDS)
  __shared__ float red[2][16][4];                 // cross-wave max/sum
  __shared__ __align__(16) WaveMem wm[4];         // 33 KB

  const int tid = threadIdx.x, wv = tid >> 6, lane = tid & 63;
  const int l15 = lane & 15, g = lane >> 4;
  const int flat = blockIdx.x;                    // 0..3071
  const int idx = (flat & 7) * 384 + (flat >> 3); // XCD chunking (3072/8)
  const int q0 = (idx & 31) * 16;
  const int zz = idx >> 5;
  const int b = zz / H, h = zz % H;

  // ---- kick off the mask copy; consumed after the QK phase ----
  {
    float4 sv = *(const float4*)(sadd_g + b * LP + tid * 4);
    *(float4*)(smask + tid * 4) = sv;
  }

  // ---- phase 1: S = K Q^T (swapped)  -> lane holds S[key][q=l15] ----
  const u16* Qp = Qb + (size_t)(b * LM + q0 + l15) * D + h * 64 + g * 8;
  bf16x8 qf0 = *(const bf16x8*)Qp;
  bf16x8 qf1 = *(const bf16x8*)(Qp + 32);
  const int k0w = wv * 256;
  const u16* Kp = KVb + (size_t)(b * LP + k0w + l15) * KV_LD + h * 64 + g * 8;

  f32x4 acc[16];
  const f32x4 z4 = {0.f, 0.f, 0.f, 0.f};
#pragma unroll
  for (int nt = 0; nt < 16; ++nt) {
    bf16x8 kf0 = *(const bf16x8*)(Kp + (size_t)nt * 16 * KV_LD);
    bf16x8 kf1 = *(const bf16x8*)(Kp + (size_t)nt * 16 * KV_LD + 32);
    f32x4 a = z4;
    a = __builtin_amdgcn_mfma_f32_16x16x32_bf16(kf0, qf0, a, 0, 0, 0);
    a = __builtin_amdgcn_mfma_f32_16x16x32_bf16(kf1, qf1, a, 0, 0, 0);
    acc[nt] = a;  // reg j: key = k0w + nt*16 + g*4 + j, q = q0 + l15
  }
  __syncthreads();  // smask visible (its writes completed long ago)

  // ---- phase 2: masked softmax (per-lane row q = l15) ----
  float mx = -1e30f;
#pragma unroll
  for (int nt = 0; nt < 16; ++nt) {
    float4 ad = *(const float4*)&smask[k0w + nt * 16 + g * 4];
#pragma unroll
    for (int j = 0; j < 4; ++j) {
      float s = acc[nt][j] * 0.125f + ((const float*)&ad)[j];
      acc[nt][j] = s;
      mx = fmaxf(mx, s);
    }
  }
  mx = fmaxf(mx, __shfl_xor(mx, 16, 64));
  mx = fmaxf(mx, __shfl_xor(mx, 32, 64));
  if (lane < 16) red[0][lane][wv] = mx;
  __syncthreads();
  mx = fmaxf(fmaxf(red[0][l15][0], red[0][l15][1]),
             fmaxf(red[0][l15][2], red[0][l15][3]));

  float sm = 0.f;
#pragma unroll
  for (int nt = 0; nt < 16; ++nt)
#pragma unroll
    for (int j = 0; j < 4; ++j) {
      float e = __expf(acc[nt][j] - mx);
      acc[nt][j] = e;
      sm += e;
    }
  sm += __shfl_xor(sm, 16, 64);
  sm += __shfl_xor(sm, 32, 64);
  if (lane < 16) red[1][lane][wv] = sm;
  __syncthreads();
  const float inv =
      1.0f / (red[1][l15][0] + red[1][l15][1] + red[1][l15][2] + red[1][l15][3]);

  // ---- normalize: pack bf16 weights into own wave's LDS segment ----
#pragma unroll
  for (int nt = 0; nt < 16; ++nt) {
    *(unsigned long long*)&wm[wv].P[l15][nt * 16 + g * 4] =
        pack4bf(acc[nt][0] * inv, acc[nt][1] * inv,
                acc[nt][2] * inv, acc[nt][3] * inv);
  }
  // (no barrier: below each wave reads only its own wm[wv].P)

  // ---- PV with interleaved NT writeout (2 rows per s-iter).
  //      Writeout: lane writes float4 at col = wv*256 + lane*4 -> one wave
  //      instr = 1024B contiguous = 8 full 128B lines, NT (bypass L2).
  const u16* Vp = Vt + (size_t)zz * 64 * LP + (size_t)l15 * LP + k0w;
  float* wbase = attnw + ((size_t)zz * LM + q0) * LP + k0w + lane * 4;
  f32x4 pacc[4];
#pragma unroll
  for (int dt = 0; dt < 4; ++dt) pacc[dt] = z4;
#pragma unroll
  for (int s = 0; s < 8; ++s) {
#pragma unroll
    for (int rr = 2 * s; rr < 2 * s + 2; ++rr) {
      union { unsigned long long ll; u16 h[4]; } u;
      u.ll = *(const unsigned long long*)&wm[wv].P[rr][lane * 4];
      f32x4 w4 = {bf2f(u.h[0]), bf2f(u.h[1]), bf2f(u.h[2]), bf2f(u.h[3])};
      __builtin_nontemporal_store(w4, (f32x4*)(wbase + (size_t)rr * LP));
    }
    bf16x8 pa = *(const bf16x8*)&wm[wv].P[l15][s * 32 + g * 8];
#pragma unroll
    for (int dt = 0; dt < 4; ++dt) {
      bf16x8 vf = *(const bf16x8*)(Vp + (size_t)dt * 16 * LP + s * 32 + g * 8);
      pacc[dt] = __builtin_amdgcn_mfma_f32_16x16x32_bf16(pa, vf, pacc[dt], 0, 0, 0);
    }
  }
  // overlay ao on P: every ao element depends (through pacc) on all P reads,
  // and no other wave reads this wave's P segment.
#pragma unroll
  for (int dt = 0; dt < 4; ++dt)
#pragma unroll
    for (int r = 0; r < 4; ++r)
      wm[wv].ao[g * 4 + r][dt * 16 + l15] = pacc[dt][r];
  __syncthreads();

  // ---- cross-wave AO reduce + bf16 store ----
  {
    const int q = tid >> 4, c4 = (tid & 15) * 4;
    float4 o0 = *(const float4*)&wm[0].ao[q][c4];
    float4 o1 = *(const float4*)&wm[1].ao[q][c4];
    float4 o2 = *(const float4*)&wm[2].ao[q][c4];
    float4 o3 = *(const float4*)&wm[3].ao[q][c4];
    u16 ob[4] = {f2bf(o0.x + o1.x + o2.x + o3.x),
                 f2bf(o0.y + o1.y + o2.y + o3.y),
                 f2bf(o0.z + o1.z + o2.z + o3.z),
                 f2bf(o0.w + o1.w + o2.w + o3.w)};
    *(unsigned long long*)&AOb[(size_t)(b * LM + q0 + q) * D + h * 64 + c4] =
        *(const unsigned long long*)ob;
  }
}

// ---------------------------------------------------------------------------
// LayerNorm(out = LN(xa + xb) * g + be), f32 + bf16 outputs (LN1).
// ---------------------------------------------------------------------------
__global__ __launch_bounds__(256) void ln_kernel(const float* __restrict__ xa,
                                                 const float* __restrict__ xb,
                                                 const float* __restrict__ g,
                                                 const float* __restrict__ be,
                                                 float* __restrict__ out,
                                                 u16* __restrict__ outb) {
  const int row = blockIdx.x;
  const float* pa = xa + (size_t)row * D;
  const float* pb = xb + (size_t)row * D;
  const int tid = threadIdx.x;
  float v[3]; float s = 0.f, ss = 0.f;
#pragma unroll
  for (int t = 0; t < 3; ++t) {
    int c = tid + t * 256;
    v[t] = pa[c] + pb[c];
    s += v[t]; ss += v[t] * v[t];
  }
  __shared__ float r1[4], r2[4];
  s = wave_reduce_sum(s);
  ss = wave_reduce_sum(ss);
  if ((tid & 63) == 0) { r1[tid >> 6] = s; r2[tid >> 6] = ss; }
  __syncthreads();
  s  = r1[0] + r1[1] + r1[2] + r1[3];
  ss = r2[0] + r2[1] + r2[2] + r2[3];
  const float mu  = s * (1.0f / D);
  const float var = ss * (1.0f / D) - mu * mu;
  const float inv = rsqrtf(var + 1e-5f);
#pragma unroll
  for (int t = 0; t < 3; ++t) {
    int c = tid + t * 256;
    float o = (v[t] - mu) * inv * g[c] + be[c];
    out[(size_t)row * D + c] = o;
    outb[(size_t)row * D + c] = f2bf(o);
  }
}

// LN over xa + xb + xc (split-K FFN2 partials), nt f32 output (LN2 -> outx;
// contiguous full-line stores so NT is safe here).
__global__ __launch_bounds__(256) void ln3_kernel(const float* __restrict__ xa,
                                                  const float* __restrict__ xb,
                                                  const float* __restrict__ xc,
                                                  const float* __restrict__ g,
                                                  const float* __restrict__ be,
                                                  float* __restrict__ out) {
  const int row = blockIdx.x;
  const float* pa = xa + (size_t)row * D;
  const float* pb = xb + (size_t)row * D;
  const float* pc = xc + (size_t)row * D;
  const int tid = threadIdx.x;
  float v[3]; float s = 0.f, ss = 0.f;
#pragma unroll
  for (int t = 0; t < 3; ++t) {
    int c = tid + t * 256;
    v[t] = pa[c] + pb[c] + pc[c];
    s += v[t]; ss += v[t] * v[t];
  }
  __shared__ float r1[4], r2[4];
  s = wave_reduce_sum(s);
  ss = wave_reduce_sum(ss);
  if ((tid & 63) == 0) { r1[tid >> 6] = s; r2[tid >> 6] = ss; }
  __syncthreads();
  s  = r1[0] + r1[1] + r1[2] + r1[3];
  ss = r2[0] + r2[1] + r2[2] + r2[3];
  const float mu  = s * (1.0f / D);
  const float var = ss * (1.0f / D) - mu * mu;
  const float inv = rsqrtf(var + 1e-5f);
#pragma unroll
  for (int t = 0; t < 3; ++t) {
    int c = tid + t * 256;
    float o = (v[t] - mu) * inv * g[c] + be[c];
    __builtin_nontemporal_store(o, &out[(size_t)row * D + c]);
  }
}

// ---------------------------------------------------------------------------
// One prep dispatch: activation casts + weight cast/transpose + additive-mask
// precompute (with all-masked guard).  Block ranges:
//   [0,1536)      mol  f32->bf16   (8 elems/thread)
//   [1536,4608)   prot f32->bf16
//   [4608,6336)   weight cast+transpose (64x64 tiles)
//   [6336,6344)   per-batch mask -> sadd f32[1024]
// ---------------------------------------------------------------------------
struct PrepArgs {
  const float* mol; const float* prot;
  u16* molb; u16* protb;
  const float* wsrc[6];
  u16* wdst[6];
  const int* mask;
  float* sadd;
};

__global__ __launch_bounds__(256) void prep_kernel(PrepArgs p) {
  __shared__ u16 L[64][72];
  __shared__ int unfl[4];
  const int bid = blockIdx.x, tid = threadIdx.x;

  if (bid < 4608) {  // activation casts
    const float* in; u16* out; int blk;
    if (bid < 1536) { in = p.mol; out = p.molb; blk = bid; }
    else            { in = p.prot; out = p.protb; blk = bid - 1536; }
    const size_t i = ((size_t)blk * 256 + tid) * 8;
    float4 a = *(const float4*)(in + i);
    float4 c = *(const float4*)(in + i + 4);
    u16 t8[8] = {f2bf(a.x), f2bf(a.y), f2bf(a.z), f2bf(a.w),
                 f2bf(c.x), f2bf(c.y), f2bf(c.z), f2bf(c.w)};
    *(int4*)(out + i) = *(const int4*)t8;
    return;
  }

  if (bid < 6336) {  // weight cast + transpose
    const int local = bid - 4608;
    constexpr int wst[6] = {0, 144, 288, 432, 576, 1152};
    int w = 0;
#pragma unroll
    for (int i = 1; i < 6; ++i)
      if (local >= wst[i]) w = i;
    const int lk = local - wst[w];
    const int Kw = (w == 5) ? 3072 : 768;
    const int Nw = (w == 4) ? 3072 : 768;
    const int tN = Nw >> 6;
    const int n0 = (lk % tN) * 64, k0 = (lk / tN) * 64;
    const float* src = p.wsrc[w];
    u16* dst = p.wdst[w];
    const int r = tid >> 3, cp = (tid & 7) * 8;
#pragma unroll
    for (int it = 0; it < 2; ++it) {
      const int row = it * 32 + r;
      float4 v0 = *(const float4*)(src + (size_t)(k0 + row) * Nw + n0 + cp);
      float4 v1 = *(const float4*)(src + (size_t)(k0 + row) * Nw + n0 + cp + 4);
      L[row][cp + 0] = f2bf(v0.x); L[row][cp + 1] = f2bf(v0.y);
      L[row][cp + 2] = f2bf(v0.z); L[row][cp + 3] = f2bf(v0.w);
      L[row][cp + 4] = f2bf(v1.x); L[row][cp + 5] = f2bf(v1.y);
      L[row][cp + 6] = f2bf(v1.z); L[row][cp + 7] = f2bf(v1.w);
    }
    __syncthreads();
#pragma unroll
    for (int it = 0; it < 2; ++it) {
      const int dd = it * 32 + r;
      u16 u[8];
#pragma unroll
      for (int i = 0; i < 8; ++i) u[i] = L[cp + i][dd];
      *(int4*)(dst + (size_t)(n0 + dd) * Kw + k0 + cp) = *(const int4*)u;
    }
    return;
  }

  // mask -> additive sadd, with all-masked guard (unmask key 0)
  {
    const int b = bid - 6336;
    const int* mrow = p.mask + b * LP;
    int4 mv = *(const int4*)(mrow + tid * 4);
    const int anyun = (!mv.x || !mv.y || !mv.z || !mv.w) ? 1 : 0;
    unsigned long long bal = __ballot(anyun);
    if ((tid & 63) == 0) unfl[tid >> 6] = (bal != 0ULL);
    __syncthreads();
    const int allm = !(unfl[0] | unfl[1] | unfl[2] | unfl[3]);
    float4 sv;
    sv.x = (mv.x && !(allm && tid == 0)) ? -1e30f : 0.f;
    sv.y = mv.y ? -1e30f : 0.f;
    sv.z = mv.z ? -1e30f : 0.f;
    sv.w = mv.w ? -1e30f : 0.f;
    *(float4*)(p.sadd + b * LP + tid * 4) = sv;
  }
}

// ---------------------------------------------------------------------------
// V transpose: KVb [B*LP][1536] (V = cols 768..1535) -> Vt [B*H][64][LP].
// grid (LP/64, B*H)
// ---------------------------------------------------------------------------
__global__ __launch_bounds__(256) void vtrans(const u16* __restrict__ KVb,
                                              u16* __restrict__ Vt) {
  const int k0 = blockIdx.x * 64;
  const int zz = blockIdx.y, b = zz / H, h = zz % H;
  __shared__ u16 L[64][72];
  const int t = threadIdx.x;
  const int r = t >> 3, cp = (t & 7) * 8;
#pragma unroll
  for (int it = 0; it < 2; ++it) {
    const int row = it * 32 + r;
    int4 v = *(const int4*)(KVb + (size_t)(b * LP + k0 + row) * KV_LD + 768 + h * 64 + cp);
    *(int4*)&L[row][cp] = v;
  }
  __syncthreads();
#pragma unroll
  for (int it = 0; it < 2; ++it) {
    const int dd = it * 32 + r;
    u16 u[8];
#pragma unroll
    for (int i = 0; i < 8; ++i) u[i] = L[cp + i][dd];
    *(int4*)(Vt + ((size_t)zz * 64 + dd) * LP + k0 + cp) = *(const int4*)u;
  }
}

}  // namespace

extern "C" void kernel_launch(void* const* d_in, const int* in_sizes, int n_in,
                              void* d_out, int out_size, void* d_ws, size_t ws_size,
                              hipStream_t stream) {
  const float* mol  = (const float*)d_in[0];
  const float* prot = (const float*)d_in[1];
  const int*   mask = (const int*)d_in[2];
  const float* Wq = (const float*)d_in[3];
  const float* Wk = (const float*)d_in[4];
  const float* Wv = (const float*)d_in[5];
  const float* Wo = (const float*)d_in[6];
  const float* bo = (const float*)d_in[7];
  const float* g1 = (const float*)d_in[8];
  const float* be1 = (const float*)d_in[9];
  const float* g2 = (const float*)d_in[10];
  const float* be2 = (const float*)d_in[11];
  const float* W1 = (const float*)d_in[12];
  const float* bf1 = (const float*)d_in[13];
  const float* W2 = (const float*)d_in[14];
  const float* bf2 = (const float*)d_in[15];

  float* outx = (float*)d_out;
  float* attn = outx + (size_t)B * LM * D;

  // ---- workspace layout (bytes), alias-packed; peak ~89.7 MB ----
  char* ws = (char*)d_ws;
  u16* molb   = (u16*)(ws + 0);           // dead after qkv -> AOb
  u16* protb  = (u16*)(ws + 6291456);     // dead after qkv -> WOout -> FFb
  u16* Qb16   = (u16*)(ws + 18874368);    // dead after fattn -> X1
  u16* KVb16  = (u16*)(ws + 25165824);    // dead after fattn/vtrans
  u16* Vt     = (u16*)(ws + 50331648);    // dead after fattn -> HIDb tail
  u16* AOb    = (u16*)(ws + 0);
  float* WOout = (float*)(ws + 6291456);
  float* FFb  = (float*)(ws + 6291456);   // FFN2 split-K partial (after LN1)
  float* X1   = (float*)(ws + 18874368);
  u16* X1b    = (u16*)(ws + 31457280);
  u16* HIDb   = (u16*)(ws + 37748736);
  float* FF   = (float*)(ws + 62914560);
  u16* Wqt  = (u16*)(ws + 75497472);
  u16* Wkvt = (u16*)(ws + 76677120);      // rows 0..767 = Wk^T, 768..1535 = Wv^T
  u16* Wot  = (u16*)(ws + 79036416);
  u16* W1t  = (u16*)(ws + 80216064);
  u16* W2t  = (u16*)(ws + 84934656);
  float* sadd = (float*)(ws + 89653248);  // 8 x 1024 f32

  dim3 t(256);

  // ---- 1: prep (casts + weight transpose + mask precompute) ----
  PrepArgs pa;
  pa.mol = mol; pa.prot = prot; pa.molb = molb; pa.protb = protb;
  pa.wsrc[0] = Wq; pa.wsrc[1] = Wk; pa.wsrc[2] = Wv; pa.wsrc[3] = Wo;
  pa.wsrc[4] = W1; pa.wsrc[5] = W2;
  pa.wdst[0] = Wqt; pa.wdst[1] = Wkvt; pa.wdst[2] = Wkvt + 768 * 768;
  pa.wdst[3] = Wot; pa.wdst[4] = W1t; pa.wdst[5] = W2t;
  pa.mask = mask; pa.sadd = sadd;
  hipLaunchKernelGGL(prep_kernel, dim3(6344), t, 0, stream, pa);

  // ---- 2: merged Q+KV projection (WM=2, 1920 blocks, 3/CU) ----
  hipLaunchKernelGGL(gemm_qkv, dim3(1920), t, 0, stream,
                     molb, protb, Wqt, Wkvt, Qb16, KVb16);

  // ---- 3: V transpose ----
  hipLaunchKernelGGL(vtrans, dim3(16, 96), t, 0, stream, KVb16, Vt);

  // ---- 4: fused attention ----
  hipLaunchKernelGGL(fattn, dim3(3072), t, 0, stream, Qb16, KVb16, Vt, sadd, attn, AOb);

  // ---- 5: output projection (WM=2, r14 config) ----
  hipLaunchKernelGGL((gemm_bf16<1, true, false, 2>), dim3(6, 64), t, 0, stream,
                     AOb, Wot, bo, WOout, nullptr, D, D, D, D);

  // ---- 6: LN1 ----
  hipLaunchKernelGGL(ln_kernel, dim3(4096), t, 0, stream, mol, WOout, g1, be1, X1, X1b);

  // ---- 7: FFN1 (+gelu), WM=2 (48KB LDS -> 3 blocks/CU) ----
  hipLaunchKernelGGL((gemm_bf16<2, false, true, 2>), dim3(24, 64), t, 0, stream,
                     X1b, W1t, bf1, nullptr, HIDb, D, D, D, 4 * D);

  // ---- 8: FFN2 split-K (WM=1, 1536 blocks) ----
  hipLaunchKernelGGL(gemm_ffn2, dim3(6, 128, 2), t, 0, stream,
                     HIDb, W2t, bf2, FF, FFb);

  // ---- 9: LN2 (3-input) ----
  hipLaunchKernelGGL(ln3_kernel, dim3(4096), t, 0, stream, X1, FF, FFb, g2, be2, outx);
}

// Round 18
// 253.650 us; speedup vs baseline: 1.0528x; 1.0528x over previous
//
#include <hip/hip_runtime.h>
#include <math.h>

namespace {

constexpr int D  = 768;
constexpr int H  = 12;
constexpr int B  = 8;
constexpr int LM = 512;
constexpr int LP = 1024;
constexpr int KV_LD = 1536;  // fused K|V projection row stride

typedef __attribute__((ext_vector_type(8))) short bf16x8;
typedef __attribute__((ext_vector_type(4))) float f32x4;
typedef unsigned short u16;

__device__ inline u16 f2bf(float f) {
  union { float f; unsigned u; } v;
  v.f = f;
  unsigned r = v.u + 0x7FFFu + ((v.u >> 16) & 1u);
  return (u16)(r >> 16);
}

__device__ inline unsigned long long pack4bf(float a, float b, float c, float d) {
  union { u16 h[4]; unsigned long long ll; } u;
  u.h[0] = f2bf(a); u.h[1] = f2bf(b); u.h[2] = f2bf(c); u.h[3] = f2bf(d);
  return u.ll;
}

__device__ inline float bf2f(u16 h) {
  union { unsigned u; float f; } v;
  v.u = ((unsigned)h) << 16;
  return v.f;
}

__device__ inline void gload16(const void* g, void* l) {
  __builtin_amdgcn_global_load_lds((const __attribute__((address_space(1))) void*)g,
                                   (__attribute__((address_space(3))) void*)l,
                                   16, 0, 0);
}

__device__ inline float wave_reduce_sum(float v) {
#pragma unroll
  for (int o = 1; o < 64; o <<= 1) v += __shfl_xor(v, o, 64);
  return v;
}

// ---------------------------------------------------------------------------
// Shared GEMM body: (32*WM) x 128 tile, BK=64, 256 threads (4 waves, 2x2).
// Double-buffered LDS, 2-phase pipeline.  Swapped-operand MFMA: lane holds
// C[row = wr+m*16+l15][col = wc+n*16+g*4+j] -> vectorized epilogue stores.
// T2 XOR swizzle via pre-swizzled global source (r11 fix, 7.1M->~0 LDS bank
// conflicts): write col-block (L&7)^(L>>3), read col-block (kk*4+g)^(l15&7).
// K-range [kbeg,kend) enables split-K callers.  bias may be runtime-null.
// sm must hold 2 * (32*WM + 128) * 64 u16 elements.  WM in {1,2,4}.
// ---------------------------------------------------------------------------
template <int EPI, bool OF32, bool OB16, int WM>
__device__ __forceinline__ void gemm_body(
    u16* sm, const u16* __restrict__ A, const u16* __restrict__ Bt,
    const float* __restrict__ bias, float* __restrict__ Cf,
    u16* __restrict__ Cb, int kbeg, int kend,
    int ldA, int ldB, int ldC, int bm, int bn) {
  constexpr int TMh = 32 * WM;
  constexpr int SSZ = (TMh + 128) * 64;
  const int tid = threadIdx.x, wv = tid >> 6, lane = tid & 63;
  const int l15 = lane & 15, g = lane >> 4;
  const int wr = (wv >> 1) * (16 * WM), wc = (wv & 1) * 64;

  f32x4 acc[WM][4];
  const f32x4 z4 = {0.f, 0.f, 0.f, 0.f};
#pragma unroll
  for (int m = 0; m < WM; ++m)
#pragma unroll
    for (int n = 0; n < 4; ++n) acc[m][n] = z4;

  // pre-swizzled global source column block: (lane&7) ^ (lane>>3)
  const int swz = (((lane & 7) ^ (lane >> 3))) * 8;
  const u16* Ab = A + (size_t)(bm + wv * 8 * WM + (lane >> 3)) * ldA + swz;
  const u16* Bb = Bt + (size_t)(bn + wv * 32 + (lane >> 3)) * ldB + swz;

  auto stage = [&](int buf, int k0) {
    u16* as = sm + buf * SSZ;
    u16* bs = as + TMh * 64;
#pragma unroll
    for (int i = 0; i < WM; ++i)
      gload16(Ab + (size_t)i * 8 * ldA + k0, &as[(wv * 8 * WM + i * 8) * 64]);
#pragma unroll
    for (int i = 0; i < 4; ++i)
      gload16(Bb + (size_t)i * 8 * ldB + k0, &bs[(wv * 32 + i * 8) * 64]);
  };

  stage(0, kbeg);
  int cur = 0;
  for (int k0 = kbeg; k0 < kend; k0 += 64) {
    __syncthreads();
    if (k0 + 64 < kend) stage(cur ^ 1, k0 + 64);
    const u16* as = sm + cur * SSZ;
    const u16* bs = as + TMh * 64;
#pragma unroll
    for (int kk = 0; kk < 2; ++kk) {
      // swizzled read col-block: (kk*4+g) ^ (row&7), row&7 == l15&7
      const int krd = ((kk * 4 + g) ^ (l15 & 7)) * 8;
      bf16x8 af[WM], bfr[4];
#pragma unroll
      for (int m = 0; m < WM; ++m)
        af[m] = *(const bf16x8*)&as[(wr + m * 16 + l15) * 64 + krd];
#pragma unroll
      for (int n = 0; n < 4; ++n)
        bfr[n] = *(const bf16x8*)&bs[(wc + n * 16 + l15) * 64 + krd];
#pragma unroll
      for (int m = 0; m < WM; ++m)
#pragma unroll
        for (int n = 0; n < 4; ++n)
          acc[m][n] =
              __builtin_amdgcn_mfma_f32_16x16x32_bf16(bfr[n], af[m], acc[m][n], 0, 0, 0);
    }
    cur ^= 1;
  }

#pragma unroll
  for (int m = 0; m < WM; ++m) {
    const size_t rr = bm + wr + m * 16 + l15;
#pragma unroll
    for (int n = 0; n < 4; ++n) {
      const int cc = bn + wc + n * 16 + g * 4;
      float v[4];
#pragma unroll
      for (int j = 0; j < 4; ++j) {
        float x = acc[m][n][j];
        if (EPI >= 1 && bias != nullptr) x += bias[cc + j];
        if (EPI == 2) x = 0.5f * x * (1.f + erff(x * 0.70710678118654752f));
        v[j] = x;
      }
      if (OF32) *(float4*)(Cf + rr * ldC + cc) = *(const float4*)v;
      if (OB16)
        *(unsigned long long*)(Cb + rr * ldC + cc) = pack4bf(v[0], v[1], v[2], v[3]);
    }
  }
}

// Generic GEMM kernel (XCD-swizzled when grid %8==0).
template <int EPI, bool OF32, bool OB16, int WM>
__global__ __launch_bounds__(256) void gemm_bf16(
    const u16* __restrict__ A, const u16* __restrict__ Bt,
    const float* __restrict__ bias, float* __restrict__ Cf,
    u16* __restrict__ Cb, int K, int ldA, int ldB, int ldC) {
  __shared__ u16 smem[2 * (32 * WM + 128) * 64];
  int bx, by;
  {
    const int total = gridDim.x * gridDim.y;
    const int flat = blockIdx.y * gridDim.x + blockIdx.x;
    if ((total & 7) == 0) {
      const int s = (flat & 7) * (total >> 3) + (flat >> 3);
      bx = s % gridDim.x;
      by = s / gridDim.x;
    } else {
      bx = blockIdx.x;
      by = blockIdx.y;
    }
  }
  gemm_body<EPI, OF32, OB16, WM>(smem, A, Bt, bias, Cf, Cb,
                                 0, K, ldA, ldB, ldC, by * 32 * WM, bx * 128);
}

// Merged Q + KV projection: one dispatch, 960 blocks (192 Q + 768 KV), WM=4.
__global__ __launch_bounds__(256) void gemm_qkv(
    const u16* __restrict__ molb, const u16* __restrict__ protb,
    const u16* __restrict__ Wqt, const u16* __restrict__ Wkvt,
    u16* __restrict__ Qb16, u16* __restrict__ KVb16) {
  __shared__ u16 smem[2 * 256 * 64];
  const int flat = blockIdx.x;                     // 0..959
  const int s = (flat & 7) * 120 + (flat >> 3);    // XCD chunking (960/8)
  if (s < 192) {
    gemm_body<0, false, true, 4>(smem, molb, Wqt, nullptr,
                                 nullptr, Qb16, 0, D, D, D, D,
                                 (s / 6) * 128, (s % 6) * 128);
  } else {
    const int t2 = s - 192;                        // 0..767
    gemm_body<0, false, true, 4>(smem, protb, Wkvt, nullptr,
                                 nullptr, KVb16, 0, D, D, D, KV_LD,
                                 (t2 / 12) * 128, (t2 % 12) * 128);
  }
}

// FFN2 split-K (K=3072 -> 2x1536): z=0 writes C0 (with bias), z=1 writes C1.
// WM=2 (64x128 tile), grid 6x64x2 = 768 blocks.
// Deterministic (no atomics); LN2 sums the partials.
__global__ __launch_bounds__(256) void gemm_ffn2(
    const u16* __restrict__ A, const u16* __restrict__ Bt,
    const float* __restrict__ bias, float* __restrict__ C0,
    float* __restrict__ C1) {
  __shared__ u16 smem[2 * (64 + 128) * 64];
  const int gx = 6, gy = 64;
  const int total = gx * gy * 2;
  const int flat = (blockIdx.z * gy + blockIdx.y) * gx + blockIdx.x;
  const int s = (flat & 7) * (total >> 3) + (flat >> 3);
  const int bx = s % gx;
  const int rem = s / gx;
  const int by = rem % gy;
  const int bz = rem / gy;
  float* Cf = bz ? C1 : C0;
  const float* bb = bz ? nullptr : bias;
  gemm_body<1, true, false, 2>(smem, A, Bt, bb, Cf, nullptr,
                               bz * 1536, bz * 1536 + 1536, 4 * D, 4 * D, D,
                               by * 64, bx * 128);
}

// ---------------------------------------------------------------------------
// Fused attention (the 254.1us-measured structure, restored exactly):
// per block = (16 q-rows, one (b,h)).  4 waves, each owns a 256-key slice.
// Swapped QK^T (mfma(K,Q)); in-lane softmax + 2 shfl; pack bf16 P to LDS;
// coalesced full-line NT writeout placed BEFORE PV (store FIFO drains under
// PV's MFMA across 4-block/CU occupancy -- r15 showed end-of-kernel
// placement exposes the drain; r17 showed interleaving breaks the V-load
// pipeline); PV MFMA; cross-wave AO reduce.
// 1D grid 3072 with bijective XCD swizzle (each XCD owns 12 whole heads).
// ---------------------------------------------------------------------------
union WaveMem {
  u16 P[16][264];     // 8448 B (row stride 528 B -> 16B-aligned rows)
  float ao[16][68];   // 4352 B
};

__global__ __launch_bounds__(256, 4) void fattn(const u16* __restrict__ Qb,
                                                const u16* __restrict__ KVb,
                                                const u16* __restrict__ Vt,
                                                const float* __restrict__ sadd_g,
                                                float* __restrict__ attnw,
                                                u16* __restrict__ AOb) {
  __shared__ float smask[LP];                     // 4 KB additive mask (LDS)
  __shared__ float red[2][16][4];                 // cross-wave max/sum
  __shared__ __align__(16) WaveMem wm[4];         // 33 KB

  const int tid = threadIdx.x, wv = tid >> 6, lane = tid & 63;
  const int l15 = lane & 15, g = lane >> 4;
  const int flat = blockIdx.x;                    // 0..3071
  const int idx = (flat & 7) * 384 + (flat >> 3); // XCD chunking (3072/8)
  const int q0 = (idx & 31) * 16;
  const int zz = idx >> 5;
  const int b = zz / H, h = zz % H;

  // ---- kick off the mask copy; consumed after the QK phase ----
  {
    float4 sv = *(const float4*)(sadd_g + b * LP + tid * 4);
    *(float4*)(smask + tid * 4) = sv;
  }

  // ---- phase 1: S = K Q^T (swapped)  -> lane holds S[key][q=l15] ----
  const u16* Qp = Qb + (size_t)(b * LM + q0 + l15) * D + h * 64 + g * 8;
  bf16x8 qf0 = *(const bf16x8*)Qp;
  bf16x8 qf1 = *(const bf16x8*)(Qp + 32);
  const int k0w = wv * 256;
  const u16* Kp = KVb + (size_t)(b * LP + k0w + l15) * KV_LD + h * 64 + g * 8;

  f32x4 acc[16];
  const f32x4 z4 = {0.f, 0.f, 0.f, 0.f};
#pragma unroll
  for (int nt = 0; nt < 16; ++nt) {
    bf16x8 kf0 = *(const bf16x8*)(Kp + (size_t)nt * 16 * KV_LD);
    bf16x8 kf1 = *(const bf16x8*)(Kp + (size_t)nt * 16 * KV_LD + 32);
    f32x4 a = z4;
    a = __builtin_amdgcn_mfma_f32_16x16x32_bf16(kf0, qf0, a, 0, 0, 0);
    a = __builtin_amdgcn_mfma_f32_16x16x32_bf16(kf1, qf1, a, 0, 0, 0);
    acc[nt] = a;  // reg j: key = k0w + nt*16 + g*4 + j, q = q0 + l15
  }
  __syncthreads();  // smask visible (its writes completed long ago)

  // ---- phase 2: masked softmax (per-lane row q = l15) ----
  float mx = -1e30f;
#pragma unroll
  for (int nt = 0; nt < 16; ++nt) {
    float4 ad = *(const float4*)&smask[k0w + nt * 16 + g * 4];
#pragma unroll
    for (int j = 0; j < 4; ++j) {
      float s = acc[nt][j] * 0.125f + ((const float*)&ad)[j];
      acc[nt][j] = s;
      mx = fmaxf(mx, s);
    }
  }
  mx = fmaxf(mx, __shfl_xor(mx, 16, 64));
  mx = fmaxf(mx, __shfl_xor(mx, 32, 64));
  if (lane < 16) red[0][lane][wv] = mx;
  __syncthreads();
  mx = fmaxf(fmaxf(red[0][l15][0], red[0][l15][1]),
             fmaxf(red[0][l15][2], red[0][l15][3]));

  float sm = 0.f;
#pragma unroll
  for (int nt = 0; nt < 16; ++nt)
#pragma unroll
    for (int j = 0; j < 4; ++j) {
      float e = __expf(acc[nt][j] - mx);
      acc[nt][j] = e;
      sm += e;
    }
  sm += __shfl_xor(sm, 16, 64);
  sm += __shfl_xor(sm, 32, 64);
  if (lane < 16) red[1][lane][wv] = sm;
  __syncthreads();
  const float inv =
      1.0f / (red[1][l15][0] + red[1][l15][1] + red[1][l15][2] + red[1][l15][3]);

  // ---- normalize: pack bf16 weights into own wave's LDS segment ----
#pragma unroll
  for (int nt = 0; nt < 16; ++nt) {
    *(unsigned long long*)&wm[wv].P[l15][nt * 16 + g * 4] =
        pack4bf(acc[nt][0] * inv, acc[nt][1] * inv,
                acc[nt][2] * inv, acc[nt][3] * inv);
  }
  // (no barrier: below each wave reads only its own wm[wv].P)

  // ---- coalesced NT attn writeout: wave streams its own 256-col slice.
  //      lane writes float4 at col = wv*256 + lane*4 -> one wave instr =
  //      1024B contiguous = 8 full 128B lines -> NT bypasses L2 cleanly.
  //      Placed BEFORE PV so the store FIFO drains under PV compute.
  {
    float* wbase = attnw + ((size_t)zz * LM + q0) * LP + k0w + lane * 4;
#pragma unroll
    for (int rr = 0; rr < 16; ++rr) {
      union { unsigned long long ll; u16 h[4]; } u;
      u.ll = *(const unsigned long long*)&wm[wv].P[rr][lane * 4];
      f32x4 w4 = {bf2f(u.h[0]), bf2f(u.h[1]), bf2f(u.h[2]), bf2f(u.h[3])};
      __builtin_nontemporal_store(w4, (f32x4*)(wbase + (size_t)rr * LP));
    }
  }

  // ---- PV: each wave multiplies its own k-slice ----
  const u16* Vp = Vt + (size_t)zz * 64 * LP + (size_t)l15 * LP + k0w;
  f32x4 pacc[4];
#pragma unroll
  for (int dt = 0; dt < 4; ++dt) pacc[dt] = z4;
#pragma unroll
  for (int s = 0; s < 8; ++s) {
    bf16x8 pa = *(const bf16x8*)&wm[wv].P[l15][s * 32 + g * 8];
#pragma unroll
    for (int dt = 0; dt < 4; ++dt) {
      bf16x8 vf = *(const bf16x8*)(Vp + (size_t)dt * 16 * LP + s * 32 + g * 8);
      pacc[dt] = __builtin_amdgcn_mfma_f32_16x16x32_bf16(pa, vf, pacc[dt], 0, 0, 0);
    }
  }
  // overlay ao on P: every ao element depends (through pacc) on all P reads,
  // and no other wave reads this wave's P segment.
#pragma unroll
  for (int dt = 0; dt < 4; ++dt)
#pragma unroll
    for (int r = 0; r < 4; ++r)
      wm[wv].ao[g * 4 + r][dt * 16 + l15] = pacc[dt][r];
  __syncthreads();

  // ---- cross-wave AO reduce + bf16 store ----
  {
    const int q = tid >> 4, c4 = (tid & 15) * 4;
    float4 o0 = *(const float4*)&wm[0].ao[q][c4];
    float4 o1 = *(const float4*)&wm[1].ao[q][c4];
    float4 o2 = *(const float4*)&wm[2].ao[q][c4];
    float4 o3 = *(const float4*)&wm[3].ao[q][c4];
    u16 ob[4] = {f2bf(o0.x + o1.x + o2.x + o3.x),
                 f2bf(o0.y + o1.y + o2.y + o3.y),
                 f2bf(o0.z + o1.z + o2.z + o3.z),
                 f2bf(o0.w + o1.w + o2.w + o3.w)};
    *(unsigned long long*)&AOb[(size_t)(b * LM + q0 + q) * D + h * 64 + c4] =
        *(const unsigned long long*)ob;
  }
}

// ---------------------------------------------------------------------------
// LayerNorm(out = LN(xa + xb) * g + be), f32 + bf16 outputs (LN1).
// ---------------------------------------------------------------------------
__global__ __launch_bounds__(256) void ln_kernel(const float* __restrict__ xa,
                                                 const float* __restrict__ xb,
                                                 const float* __restrict__ g,
                                                 const float* __restrict__ be,
                                                 float* __restrict__ out,
                                                 u16* __restrict__ outb) {
  const int row = blockIdx.x;
  const float* pa = xa + (size_t)row * D;
  const float* pb = xb + (size_t)row * D;
  const int tid = threadIdx.x;
  float v[3]; float s = 0.f, ss = 0.f;
#pragma unroll
  for (int t = 0; t < 3; ++t) {
    int c = tid + t * 256;
    v[t] = pa[c] + pb[c];
    s += v[t]; ss += v[t] * v[t];
  }
  __shared__ float r1[4], r2[4];
  s = wave_reduce_sum(s);
  ss = wave_reduce_sum(ss);
  if ((tid & 63) == 0) { r1[tid >> 6] = s; r2[tid >> 6] = ss; }
  __syncthreads();
  s  = r1[0] + r1[1] + r1[2] + r1[3];
  ss = r2[0] + r2[1] + r2[2] + r2[3];
  const float mu  = s * (1.0f / D);
  const float var = ss * (1.0f / D) - mu * mu;
  const float inv = rsqrtf(var + 1e-5f);
#pragma unroll
  for (int t = 0; t < 3; ++t) {
    int c = tid + t * 256;
    float o = (v[t] - mu) * inv * g[c] + be[c];
    out[(size_t)row * D + c] = o;
    outb[(size_t)row * D + c] = f2bf(o);
  }
}

// LN over xa + xb + xc (split-K FFN2 partials), nt f32 output (LN2 -> outx;
// contiguous full-line stores so NT is safe here).
__global__ __launch_bounds__(256) void ln3_kernel(const float* __restrict__ xa,
                                                  const float* __restrict__ xb,
                                                  const float* __restrict__ xc,
                                                  const float* __restrict__ g,
                                                  const float* __restrict__ be,
                                                  float* __restrict__ out) {
  const int row = blockIdx.x;
  const float* pa = xa + (size_t)row * D;
  const float* pb = xb + (size_t)row * D;
  const float* pc = xc + (size_t)row * D;
  const int tid = threadIdx.x;
  float v[3]; float s = 0.f, ss = 0.f;
#pragma unroll
  for (int t = 0; t < 3; ++t) {
    int c = tid + t * 256;
    v[t] = pa[c] + pb[c] + pc[c];
    s += v[t]; ss += v[t] * v[t];
  }
  __shared__ float r1[4], r2[4];
  s = wave_reduce_sum(s);
  ss = wave_reduce_sum(ss);
  if ((tid & 63) == 0) { r1[tid >> 6] = s; r2[tid >> 6] = ss; }
  __syncthreads();
  s  = r1[0] + r1[1] + r1[2] + r1[3];
  ss = r2[0] + r2[1] + r2[2] + r2[3];
  const float mu  = s * (1.0f / D);
  const float var = ss * (1.0f / D) - mu * mu;
  const float inv = rsqrtf(var + 1e-5f);
#pragma unroll
  for (int t = 0; t < 3; ++t) {
    int c = tid + t * 256;
    float o = (v[t] - mu) * inv * g[c] + be[c];
    __builtin_nontemporal_store(o, &out[(size_t)row * D + c]);
  }
}

// ---------------------------------------------------------------------------
// One prep dispatch: activation casts + weight cast/transpose + additive-mask
// precompute (with all-masked guard).  Block ranges:
//   [0,1536)      mol  f32->bf16   (8 elems/thread)
//   [1536,4608)   prot f32->bf16
//   [4608,6336)   weight cast+transpose (64x64 tiles)
//   [6336,6344)   per-batch mask -> sadd f32[1024]
// ---------------------------------------------------------------------------
struct PrepArgs {
  const float* mol; const float* prot;
  u16* molb; u16* protb;
  const float* wsrc[6];
  u16* wdst[6];
  const int* mask;
  float* sadd;
};

__global__ __launch_bounds__(256) void prep_kernel(PrepArgs p) {
  __shared__ u16 L[64][72];
  __shared__ int unfl[4];
  const int bid = blockIdx.x, tid = threadIdx.x;

  if (bid < 4608) {  // activation casts
    const float* in; u16* out; int blk;
    if (bid < 1536) { in = p.mol; out = p.molb; blk = bid; }
    else            { in = p.prot; out = p.protb; blk = bid - 1536; }
    const size_t i = ((size_t)blk * 256 + tid) * 8;
    float4 a = *(const float4*)(in + i);
    float4 c = *(const float4*)(in + i + 4);
    u16 t8[8] = {f2bf(a.x), f2bf(a.y), f2bf(a.z), f2bf(a.w),
                 f2bf(c.x), f2bf(c.y), f2bf(c.z), f2bf(c.w)};
    *(int4*)(out + i) = *(const int4*)t8;
    return;
  }

  if (bid < 6336) {  // weight cast + transpose
    const int local = bid - 4608;
    constexpr int wst[6] = {0, 144, 288, 432, 576, 1152};
    int w = 0;
#pragma unroll
    for (int i = 1; i < 6; ++i)
      if (local >= wst[i]) w = i;
    const int lk = local - wst[w];
    const int Kw = (w == 5) ? 3072 : 768;
    const int Nw = (w == 4) ? 3072 : 768;
    const int tN = Nw >> 6;
    const int n0 = (lk % tN) * 64, k0 = (lk / tN) * 64;
    const float* src = p.wsrc[w];
    u16* dst = p.wdst[w];
    const int r = tid >> 3, cp = (tid & 7) * 8;
#pragma unroll
    for (int it = 0; it < 2; ++it) {
      const int row = it * 32 + r;
      float4 v0 = *(const float4*)(src + (size_t)(k0 + row) * Nw + n0 + cp);
      float4 v1 = *(const float4*)(src + (size_t)(k0 + row) * Nw + n0 + cp + 4);
      L[row][cp + 0] = f2bf(v0.x); L[row][cp + 1] = f2bf(v0.y);
      L[row][cp + 2] = f2bf(v0.z); L[row][cp + 3] = f2bf(v0.w);
      L[row][cp + 4] = f2bf(v1.x); L[row][cp + 5] = f2bf(v1.y);
      L[row][cp + 6] = f2bf(v1.z); L[row][cp + 7] = f2bf(v1.w);
    }
    __syncthreads();
#pragma unroll
    for (int it = 0; it < 2; ++it) {
      const int dd = it * 32 + r;
      u16 u[8];
#pragma unroll
      for (int i = 0; i < 8; ++i) u[i] = L[cp + i][dd];
      *(int4*)(dst + (size_t)(n0 + dd) * Kw + k0 + cp) = *(const int4*)u;
    }
    return;
  }

  // mask -> additive sadd, with all-masked guard (unmask key 0)
  {
    const int b = bid - 6336;
    const int* mrow = p.mask + b * LP;
    int4 mv = *(const int4*)(mrow + tid * 4);
    const int anyun = (!mv.x || !mv.y || !mv.z || !mv.w) ? 1 : 0;
    unsigned long long bal = __ballot(anyun);
    if ((tid & 63) == 0) unfl[tid >> 6] = (bal != 0ULL);
    __syncthreads();
    const int allm = !(unfl[0] | unfl[1] | unfl[2] | unfl[3]);
    float4 sv;
    sv.x = (mv.x && !(allm && tid == 0)) ? -1e30f : 0.f;
    sv.y = mv.y ? -1e30f : 0.f;
    sv.z = mv.z ? -1e30f : 0.f;
    sv.w = mv.w ? -1e30f : 0.f;
    *(float4*)(p.sadd + b * LP + tid * 4) = sv;
  }
}

// ---------------------------------------------------------------------------
// V transpose: KVb [B*LP][1536] (V = cols 768..1535) -> Vt [B*H][64][LP].
// grid (LP/64, B*H)
// ---------------------------------------------------------------------------
__global__ __launch_bounds__(256) void vtrans(const u16* __restrict__ KVb,
                                              u16* __restrict__ Vt) {
  const int k0 = blockIdx.x * 64;
  const int zz = blockIdx.y, b = zz / H, h = zz % H;
  __shared__ u16 L[64][72];
  const int t = threadIdx.x;
  const int r = t >> 3, cp = (t & 7) * 8;
#pragma unroll
  for (int it = 0; it < 2; ++it) {
    const int row = it * 32 + r;
    int4 v = *(const int4*)(KVb + (size_t)(b * LP + k0 + row) * KV_LD + 768 + h * 64 + cp);
    *(int4*)&L[row][cp] = v;
  }
  __syncthreads();
#pragma unroll
  for (int it = 0; it < 2; ++it) {
    const int dd = it * 32 + r;
    u16 u[8];
#pragma unroll
    for (int i = 0; i < 8; ++i) u[i] = L[cp + i][dd];
    *(int4*)(Vt + ((size_t)zz * 64 + dd) * LP + k0 + cp) = *(const int4*)u;
  }
}

}  // namespace

extern "C" void kernel_launch(void* const* d_in, const int* in_sizes, int n_in,
                              void* d_out, int out_size, void* d_ws, size_t ws_size,
                              hipStream_t stream) {
  const float* mol  = (const float*)d_in[0];
  const float* prot = (const float*)d_in[1];
  const int*   mask = (const int*)d_in[2];
  const float* Wq = (const float*)d_in[3];
  const float* Wk = (const float*)d_in[4];
  const float* Wv = (const float*)d_in[5];
  const float* Wo = (const float*)d_in[6];
  const float* bo = (const float*)d_in[7];
  const float* g1 = (const float*)d_in[8];
  const float* be1 = (const float*)d_in[9];
  const float* g2 = (const float*)d_in[10];
  const float* be2 = (const float*)d_in[11];
  const float* W1 = (const float*)d_in[12];
  const float* bf1 = (const float*)d_in[13];
  const float* W2 = (const float*)d_in[14];
  const float* bf2 = (const float*)d_in[15];

  float* outx = (float*)d_out;
  float* attn = outx + (size_t)B * LM * D;

  // ---- workspace layout (bytes), alias-packed; peak ~89.7 MB ----
  char* ws = (char*)d_ws;
  u16* molb   = (u16*)(ws + 0);           // dead after qkv -> AOb
  u16* protb  = (u16*)(ws + 6291456);     // dead after qkv -> WOout -> FFb
  u16* Qb16   = (u16*)(ws + 18874368);    // dead after fattn -> X1
  u16* KVb16  = (u16*)(ws + 25165824);    // dead after fattn/vtrans
  u16* Vt     = (u16*)(ws + 50331648);    // dead after fattn -> HIDb tail
  u16* AOb    = (u16*)(ws + 0);
  float* WOout = (float*)(ws + 6291456);
  float* FFb  = (float*)(ws + 6291456);   // FFN2 split-K partial (after LN1)
  float* X1   = (float*)(ws + 18874368);
  u16* X1b    = (u16*)(ws + 31457280);
  u16* HIDb   = (u16*)(ws + 37748736);
  float* FF   = (float*)(ws + 62914560);
  u16* Wqt  = (u16*)(ws + 75497472);
  u16* Wkvt = (u16*)(ws + 76677120);      // rows 0..767 = Wk^T, 768..1535 = Wv^T
  u16* Wot  = (u16*)(ws + 79036416);
  u16* W1t  = (u16*)(ws + 80216064);
  u16* W2t  = (u16*)(ws + 84934656);
  float* sadd = (float*)(ws + 89653248);  // 8 x 1024 f32

  dim3 t(256);

  // ---- 1: prep (casts + weight transpose + mask precompute) ----
  PrepArgs pa;
  pa.mol = mol; pa.prot = prot; pa.molb = molb; pa.protb = protb;
  pa.wsrc[0] = Wq; pa.wsrc[1] = Wk; pa.wsrc[2] = Wv; pa.wsrc[3] = Wo;
  pa.wsrc[4] = W1; pa.wsrc[5] = W2;
  pa.wdst[0] = Wqt; pa.wdst[1] = Wkvt; pa.wdst[2] = Wkvt + 768 * 768;
  pa.wdst[3] = Wot; pa.wdst[4] = W1t; pa.wdst[5] = W2t;
  pa.mask = mask; pa.sadd = sadd;
  hipLaunchKernelGGL(prep_kernel, dim3(6344), t, 0, stream, pa);

  // ---- 2: merged Q+KV projection (WM=4, 960 blocks) ----
  hipLaunchKernelGGL(gemm_qkv, dim3(960), t, 0, stream,
                     molb, protb, Wqt, Wkvt, Qb16, KVb16);

  // ---- 3: V transpose ----
  hipLaunchKernelGGL(vtrans, dim3(16, 96), t, 0, stream, KVb16, Vt);

  // ---- 4: fused attention ----
  hipLaunchKernelGGL(fattn, dim3(3072), t, 0, stream, Qb16, KVb16, Vt, sadd, attn, AOb);

  // ---- 5: output projection (WM=2) ----
  hipLaunchKernelGGL((gemm_bf16<1, true, false, 2>), dim3(6, 64), t, 0, stream,
                     AOb, Wot, bo, WOout, nullptr, D, D, D, D);

  // ---- 6: LN1 ----
  hipLaunchKernelGGL(ln_kernel, dim3(4096), t, 0, stream, mol, WOout, g1, be1, X1, X1b);

  // ---- 7: FFN1 (+gelu), WM=2 (48KB LDS -> 3 blocks/CU) ----
  hipLaunchKernelGGL((gemm_bf16<2, false, true, 2>), dim3(24, 64), t, 0, stream,
                     X1b, W1t, bf1, nullptr, HIDb, D, D, D, 4 * D);

  // ---- 8: FFN2 split-K (WM=2, 768 blocks) ----
  hipLaunchKernelGGL(gemm_ffn2, dim3(6, 64, 2), t, 0, stream,
                     HIDb, W2t, bf2, FF, FFb);

  // ---- 9: LN2 (3-input) ----
  hipLaunchKernelGGL(ln3_kernel, dim3(4096), t, 0, stream, X1, FF, FFb, g2, be2, outx);
}